// Round 5
// baseline (599.637 us; speedup 1.0000x reference)
//
#include <hip/hip_runtime.h>
#include <stdint.h>

#define N_NODES 50000
#define N_EDGES 800000
#define CAP 96            // max tracked in-degree; Poisson(16) tops out ~45
#define NTILES (N_EDGES/16)

typedef _Float16 f16x8 __attribute__((ext_vector_type(8)));
typedef _Float16 f16x2 __attribute__((ext_vector_type(2)));
typedef float    f32x4 __attribute__((ext_vector_type(4)));

// ---------------- K1: f = fctp_scalar(x, attr, W_l1_0, W_l1_1) ----------------
__global__ __launch_bounds__(128) void k_node_f(
        const float* __restrict__ x, const float* __restrict__ attr,
        const float* __restrict__ W0, const float* __restrict__ W1,
        float* __restrict__ f)
{
    int n = blockIdx.x;
    int t = threadIdx.x;
    __shared__ float xs[128];
    xs[t] = x[(size_t)n*128 + t];
    __syncthreads();
    float a = attr[n] * 0.17677669529663689f;   // attr / sqrt(32)
    float acc = 0.f;
    if (t < 32) {
        #pragma unroll
        for (int u = 0; u < 32; ++u) acc += xs[u] * W0[u*32 + t];
    } else {
        int c = t - 32; int w = c / 3, d = c - 3*w;
        #pragma unroll
        for (int u = 0; u < 32; ++u) acc += xs[32 + u*3 + d] * W1[u*32 + w];
    }
    f[(size_t)n*128 + t] = acc * a;
}

// ---------------- K2: per-dst edge lists (atomic ticket) ----------------
__global__ void k_zero(int* __restrict__ cnt) {
    int i = blockIdx.x*256 + threadIdx.x;
    if (i < N_NODES) cnt[i] = 0;
}

__global__ void k_ticket(const int* __restrict__ dst, int* __restrict__ cnt,
                         int* __restrict__ idx) {
    int e = blockIdx.x*256 + threadIdx.x;
    if (e >= N_EDGES) return;
    int d = dst[e];
    int slot = atomicAdd(&cnt[d], 1);
    if (slot < CAP) idx[d*CAP + slot] = e;
}

// ---------------- K3: edge-parallel MLP -> weight[e][128] f16 ----------------
// Output layout per edge row (dword pairs): dwords [0,32) = (wA[u]*e0*0.25, wC[u]*0.25),
// dwords [32,64) = (wD[u]*e0*0.25, wB[u]*0.25/sqrt3).  One dword per (half,u).
__global__ __launch_bounds__(256) void k_edge_w(
    const float* __restrict__ escal, const float* __restrict__ eattr,
    const float* __restrict__ Wfc1, const float* __restrict__ Wfc2,
    _Float16* __restrict__ weight)
{
    __shared__ __align__(16) _Float16 lds_h[4][16][72];
    __shared__ __align__(16) uint32_t lds_o[4][16][64];

    const int wv   = threadIdx.x >> 6;
    const int lane = threadIdx.x & 63;
    const int rl   = lane & 15;
    const int g4   = lane >> 4;

    // MFMA B-fragments of W_fc1/W_fc2 (f16, 1/8 folded)
    f16x8 w1f[2][4];
    #pragma unroll
    for (int ks = 0; ks < 2; ++ks)
      #pragma unroll
      for (int jt = 0; jt < 4; ++jt)
        #pragma unroll
        for (int i = 0; i < 8; ++i)
          w1f[ks][jt][i] = (_Float16)(Wfc1[(ks*32 + g4*8 + i)*64 + jt*16 + rl] * 0.125f);
    f16x8 w2f[2][8];
    #pragma unroll
    for (int ks = 0; ks < 2; ++ks)
      #pragma unroll
      for (int jt = 0; jt < 8; ++jt)
        #pragma unroll
        for (int i = 0; i < 8; ++i)
          w2f[ks][jt][i] = (_Float16)(Wfc2[(ks*32 + g4*8 + i)*128 + jt*16 + rl] * 0.125f);

    const int w  = blockIdx.x*4 + wv;
    const int t0 = w*7;
    const int t1 = (t0 + 7 < NTILES) ? t0 + 7 : NTILES;

    for (int tt = t0; tt < t1; ++tt) {
        const int eb = tt*16;
        // A-frags: 16 edge rows of escal
        f16x8 af[2];
        #pragma unroll
        for (int ks = 0; ks < 2; ++ks) {
            const float* p = escal + (size_t)(eb + rl)*64 + ks*32 + g4*8;
            float4 lo = *(const float4*)(p);
            float4 hi = *(const float4*)(p + 4);
            af[ks][0]=(_Float16)lo.x; af[ks][1]=(_Float16)lo.y;
            af[ks][2]=(_Float16)lo.z; af[ks][3]=(_Float16)lo.w;
            af[ks][4]=(_Float16)hi.x; af[ks][5]=(_Float16)hi.y;
            af[ks][6]=(_Float16)hi.z; af[ks][7]=(_Float16)hi.w;
        }
        float e0L = eattr[(size_t)(eb + rl)*4];

        // h = es @ (W1/8)
        f32x4 hacc[4];
        #pragma unroll
        for (int jt = 0; jt < 4; ++jt) {
            f32x4 z = {0.f,0.f,0.f,0.f};
            z = __builtin_amdgcn_mfma_f32_16x16x32_f16(af[0], w1f[0][jt], z, 0,0,0);
            z = __builtin_amdgcn_mfma_f32_16x16x32_f16(af[1], w1f[1][jt], z, 0,0,0);
            hacc[jt] = z;
        }
        // silu*1.679, transpose via LDS
        #pragma unroll
        for (int jt = 0; jt < 4; ++jt)
          #pragma unroll
          for (int r = 0; r < 4; ++r) {
            float v = hacc[jt][r];
            float s = 1.679f * v / (1.f + __expf(-v));
            lds_h[wv][g4*4 + r][jt*16 + rl] = (_Float16)s;
          }
        f16x8 a2[2];
        #pragma unroll
        for (int ks = 0; ks < 2; ++ks)
            a2[ks] = *reinterpret_cast<const f16x8*>(&lds_h[wv][rl][ks*32 + g4*8]);

        // wfull = h @ (W2/8)
        f32x4 z[8];
        #pragma unroll
        for (int jt = 0; jt < 8; ++jt) {
            f32x4 zz = {0.f,0.f,0.f,0.f};
            zz = __builtin_amdgcn_mfma_f32_16x16x32_f16(a2[0], w2f[0][jt], zz, 0,0,0);
            zz = __builtin_amdgcn_mfma_f32_16x16x32_f16(a2[1], w2f[1][jt], zz, 0,0,0);
            z[jt] = zz;
        }

        // scale + permute into dword pairs, f16 pack
        #pragma unroll
        for (int pg = 0; pg < 2; ++pg)
          #pragma unroll
          for (int r = 0; r < 4; ++r) {
            float e0r = __shfl(e0L, g4*4 + r);
            float loA = z[pg][r]     * (0.25f * e0r);
            float hiC = z[2 + pg][r] * 0.25f;
            float loD = z[4 + pg][r] * (0.25f * e0r);
            float hiB = z[6 + pg][r] * 0.14433756729740643f;   // 0.25/sqrt(3)
            uint32_t pAC = __builtin_bit_cast(uint32_t, __builtin_amdgcn_cvt_pkrtz(loA, hiC));
            uint32_t pDB = __builtin_bit_cast(uint32_t, __builtin_amdgcn_cvt_pkrtz(loD, hiB));
            lds_o[wv][g4*4 + r][pg*16 + rl]      = pAC;
            lds_o[wv][g4*4 + r][32 + pg*16 + rl] = pDB;
          }

        // coalesced copy-out: 16 rows x 256B
        uint32_t* wg = (uint32_t*)weight + (size_t)tt*1024;
        const uint32_t* lo32 = &lds_o[wv][0][0];
        #pragma unroll
        for (int p = 0; p < 4; ++p) {
            uint4 v = *(const uint4*)(lo32 + p*256 + lane*4);
            *(uint4*)(wg + p*256 + lane*4) = v;
        }
    }
}

// ---------------- K4: gather + reduce + node transform (no MFMA) ----------------
__global__ __launch_bounds__(256, 8) void k_main(
    const float* __restrict__ x, const float* __restrict__ attr,
    const int*   __restrict__ esrc, const float* __restrict__ eattr,
    const _Float16* __restrict__ weight,
    const float* __restrict__ Wsc0, const float* __restrict__ Wsc1,
    const float* __restrict__ WA0,  const float* __restrict__ WB0,
    const float* __restrict__ WC1,  const float* __restrict__ WD1,
    const float* __restrict__ W3A,  const float* __restrict__ W3B,
    const float* __restrict__ f,    const int* __restrict__ cnt,
    const int*   __restrict__ idx,  float* __restrict__ out)
{
    __shared__ float lds_m[4][256];   // mA[0,32) mB[32,64) mC[64,160) mD[160,256)

    const int wv   = threadIdx.x >> 6;
    const int lane = threadIdx.x & 63;
    const int u    = lane & 31;
    const int half = lane >> 5;
    const int node = blockIdx.x*4 + wv;
    if (node >= N_NODES) return;

    const uint32_t* wq = (const uint32_t*)weight;
    int deg = min(cnt[node], CAP);

    float mAB = 0.f, mCD0 = 0.f, mCD1 = 0.f, mCD2 = 0.f;

    for (int tb = 0; tb < deg; tb += 64) {
        int myi  = tb + lane;
        int eidL = (myi < deg) ? idx[node*CAP + myi] : 0;
        int srcL = (myi < deg) ? esrc[eidL] : 0;
        float4 eaT = make_float4(0.f,0.f,0.f,0.f);
        if (myi < deg) eaT = *(const float4*)(eattr + (size_t)eidL*4);
        int rows = min(64, deg - tb);

        for (int b = 0; b < rows; b += 8) {
            int nb = min(8, rows - b);
            uint32_t wp[8]; float gA[8], gB[8], gC[8];
            #pragma unroll
            for (int j = 0; j < 8; ++j) if (j < nb) {
                int mm = b + j;
                int e  = __shfl(eidL, mm);
                int sm = __shfl(srcL, mm);
                wp[j] = wq[(size_t)e*64 + half*32 + u];
                const float* gb = f + (size_t)sm*128;
                if (half == 0) { gA[j] = gb[u]; }
                else { gA[j] = gb[32 + u*3]; gB[j] = gb[33 + u*3]; gC[j] = gb[34 + u*3]; }
            }
            #pragma unroll
            for (int j = 0; j < 8; ++j) if (j < nb) {
                int mm = b + j;
                float e1x = __shfl(eaT.y, mm);
                float e1y = __shfl(eaT.z, mm);
                float e1z = __shfl(eaT.w, mm);
                f16x2 wh = __builtin_bit_cast(f16x2, wp[j]);
                float lo = (float)wh[0], hi = (float)wh[1];
                if (half == 0) {
                    mAB += lo * gA[j];                       // mA (e0,0.25 folded)
                    float tc = hi * gA[j];                   // wC*g0*0.25
                    mCD0 += tc*e1x; mCD1 += tc*e1y; mCD2 += tc*e1z;
                } else {
                    mAB += hi * (gA[j]*e1x + gB[j]*e1y + gC[j]*e1z);  // mB
                    mCD0 += lo*gA[j]; mCD1 += lo*gB[j]; mCD2 += lo*gC[j];  // mD
                }
            }
        }
    }

    float* M = lds_m[wv];
    if (half == 0) {
        M[u] = mAB;
        M[64  + u*3 + 0] = mCD0; M[64  + u*3 + 1] = mCD1; M[64  + u*3 + 2] = mCD2;
    } else {
        M[32 + u] = mAB;
        M[160 + u*3 + 0] = mCD0; M[160 + u*3 + 1] = mCD1; M[160 + u*3 + 2] = mCD2;
    }

    float a    = attr[node];
    float a8   = a * 0.125f;
    float as32 = a * 0.17677669529663689f;

    const float w3 = (half == 0) ? W3A[u] : W3B[u];
    float tpart = (half == 0) ? M[u] * w3 : M[32 + u] * w3;
    #pragma unroll
    for (int off = 32; off > 0; off >>= 1) tpart += __shfl_xor(tpart, off);
    float angle = 0.1f * tpart * a8;
    float sn, cs; __sincosf(angle, &sn, &cs);

    const float* xr = x + (size_t)node*128;
    #pragma unroll
    for (int pass = 0; pass < 2; ++pass) {
        int c = lane + pass*64;
        float accC, accS;
        if (c < 32) {
            float s1 = 0.f, s2 = 0.f;
            #pragma unroll
            for (int uu = 0; uu < 32; ++uu) {
                s1 += M[uu]      * WA0[uu*32 + c]
                   +  M[32 + uu] * WB0[uu*32 + c];
                s2 += xr[uu] * Wsc0[uu*32 + c];
            }
            accC = s1 * a8; accS = s2 * as32;
        } else {
            int cc = c - 32; int w = cc / 3, d = cc - 3*w;
            float s1 = 0.f, s2 = 0.f;
            #pragma unroll
            for (int uu = 0; uu < 32; ++uu) {
                s1 += M[64  + uu*3 + d] * WC1[uu*32 + w]
                   +  M[160 + uu*3 + d] * WD1[uu*32 + w];
                s2 += xr[32 + uu*3 + d] * Wsc1[uu*32 + w];
            }
            accC = s1 * a8; accS = s2 * as32;
        }
        out[(size_t)node*128 + c] = cs*accS + sn*accC;
    }
}

// ---------------- Fallback: R1 fused kernel (used when ws too small) ----------------
__global__ __launch_bounds__(256) void k_main_fused(
    const float* __restrict__ x, const float* __restrict__ attr,
    const int*   __restrict__ esrc, const float* __restrict__ eattr,
    const float* __restrict__ escal,
    const float* __restrict__ Wsc0, const float* __restrict__ Wsc1,
    const float* __restrict__ Wfc1, const float* __restrict__ Wfc2,
    const float* __restrict__ WA0,  const float* __restrict__ WB0,
    const float* __restrict__ WC1,  const float* __restrict__ WD1,
    const float* __restrict__ W3A,  const float* __restrict__ W3B,
    const float* __restrict__ f,    const int* __restrict__ cnt,
    const int*   __restrict__ idx,  float* __restrict__ out)
{
    __shared__ __align__(16) _Float16 lds_h[4][16][72];
    __shared__ float lds_w[4][16][132];
    __shared__ float lds_m[4][256];

    const int wv   = threadIdx.x >> 6;
    const int lane = threadIdx.x & 63;
    const int node = blockIdx.x*4 + wv;
    if (node >= N_NODES) return;
    const int rl   = lane & 15;
    const int g4   = lane >> 4;
    const int u    = lane & 31;
    const int half = lane >> 5;

    f16x8 w1f[2][4];
    #pragma unroll
    for (int ks = 0; ks < 2; ++ks)
      #pragma unroll
      for (int jt = 0; jt < 4; ++jt)
        #pragma unroll
        for (int i = 0; i < 8; ++i)
          w1f[ks][jt][i] = (_Float16)(Wfc1[(ks*32 + g4*8 + i)*64 + jt*16 + rl] * 0.125f);
    f16x8 w2f[2][8];
    #pragma unroll
    for (int ks = 0; ks < 2; ++ks)
      #pragma unroll
      for (int jt = 0; jt < 8; ++jt)
        #pragma unroll
        for (int i = 0; i < 8; ++i)
          w2f[ks][jt][i] = (_Float16)(Wfc2[(ks*32 + g4*8 + i)*128 + jt*16 + rl] * 0.125f);

    int deg  = min(cnt[node], CAP);
    int eid0 = (lane      < deg) ? idx[node*CAP + lane]      : 0;
    int eid1 = (lane + 64 < deg) ? idx[node*CAP + 64 + lane] : 0;

    float mAB = 0.f, mCD0 = 0.f, mCD1 = 0.f, mCD2 = 0.f;

    int ntile = (deg + 15) >> 4;
    for (int t = 0; t < ntile; ++t) {
        int sl = t*16 + rl; sl = min(sl, deg - 1);
        int eA = __shfl(eid0, sl & 63);
        int eB = __shfl(eid1, (sl - 64) & 63);
        int er = (sl < 64) ? eA : eB;
        f16x8 af[2];
        #pragma unroll
        for (int ks = 0; ks < 2; ++ks) {
            const float* p = escal + (size_t)er*64 + ks*32 + g4*8;
            float4 lo = *(const float4*)(p);
            float4 hi = *(const float4*)(p + 4);
            af[ks][0]=(_Float16)lo.x; af[ks][1]=(_Float16)lo.y;
            af[ks][2]=(_Float16)lo.z; af[ks][3]=(_Float16)lo.w;
            af[ks][4]=(_Float16)hi.x; af[ks][5]=(_Float16)hi.y;
            af[ks][6]=(_Float16)hi.z; af[ks][7]=(_Float16)hi.w;
        }

        f32x4 hacc[4];
        #pragma unroll
        for (int jt = 0; jt < 4; ++jt) {
            f32x4 z = {0.f,0.f,0.f,0.f};
            z = __builtin_amdgcn_mfma_f32_16x16x32_f16(af[0], w1f[0][jt], z, 0,0,0);
            z = __builtin_amdgcn_mfma_f32_16x16x32_f16(af[1], w1f[1][jt], z, 0,0,0);
            hacc[jt] = z;
        }
        #pragma unroll
        for (int jt = 0; jt < 4; ++jt)
          #pragma unroll
          for (int r = 0; r < 4; ++r) {
            float v = hacc[jt][r];
            float s = 1.679f * v / (1.f + __expf(-v));
            lds_h[wv][g4*4 + r][jt*16 + rl] = (_Float16)s;
          }
        f16x8 a2[2];
        #pragma unroll
        for (int ks = 0; ks < 2; ++ks)
            a2[ks] = *reinterpret_cast<const f16x8*>(&lds_h[wv][rl][ks*32 + g4*8]);

        #pragma unroll
        for (int jt = 0; jt < 8; ++jt) {
            f32x4 z = {0.f,0.f,0.f,0.f};
            z = __builtin_amdgcn_mfma_f32_16x16x32_f16(a2[0], w2f[0][jt], z, 0,0,0);
            z = __builtin_amdgcn_mfma_f32_16x16x32_f16(a2[1], w2f[1][jt], z, 0,0,0);
            #pragma unroll
            for (int r = 0; r < 4; ++r)
                lds_w[wv][g4*4 + r][jt*16 + rl] = z[r];
        }

        int rows = min(16, deg - t*16);
        for (int mm = 0; mm < rows; ++mm) {
            int s2 = t*16 + mm;
            int e = (s2 < 64) ? __shfl(eid0, s2) : __shfl(eid1, (s2 - 64) & 63);
            e = __builtin_amdgcn_readfirstlane(e);
            int   src  = esrc[e];
            float ea0  = eattr[(size_t)e*4 + 0];
            float ea1x = eattr[(size_t)e*4 + 1];
            float ea1y = eattr[(size_t)e*4 + 2];
            float ea1z = eattr[(size_t)e*4 + 3];
            float wPr = lds_w[wv][mm][half*64 + u];
            float wSe = lds_w[wv][mm][32 + half*64 + u];
            const float* gb = f + (size_t)src*128;
            if (half == 0) {
                float g0 = gb[u];
                mAB += wPr * g0 * ea0;
                float tc = wSe * g0;
                mCD0 += tc * ea1x; mCD1 += tc * ea1y; mCD2 += tc * ea1z;
            } else {
                float g1x = gb[32 + u*3 + 0];
                float g1y = gb[32 + u*3 + 1];
                float g1z = gb[32 + u*3 + 2];
                float dotB = g1x*ea1x + g1y*ea1y + g1z*ea1z;
                mAB += wSe * dotB * 0.57735026918962576f;
                float td = wPr * ea0;
                mCD0 += td*g1x; mCD1 += td*g1y; mCD2 += td*g1z;
            }
        }
    }

    mAB *= 0.25f; mCD0 *= 0.25f; mCD1 *= 0.25f; mCD2 *= 0.25f;

    float* M = lds_m[wv];
    if (half == 0) {
        M[u] = mAB;
        M[64  + u*3 + 0] = mCD0; M[64  + u*3 + 1] = mCD1; M[64  + u*3 + 2] = mCD2;
    } else {
        M[32 + u] = mAB;
        M[160 + u*3 + 0] = mCD0; M[160 + u*3 + 1] = mCD1; M[160 + u*3 + 2] = mCD2;
    }

    float a    = attr[node];
    float a8   = a * 0.125f;
    float as32 = a * 0.17677669529663689f;

    const float w3 = (half == 0) ? W3A[u] : W3B[u];
    float tpart = (half == 0) ? M[u] * w3 : M[32 + u] * w3;
    #pragma unroll
    for (int off = 32; off > 0; off >>= 1) tpart += __shfl_xor(tpart, off);
    float angle = 0.1f * tpart * a8;
    float sn, cs; __sincosf(angle, &sn, &cs);

    const float* xr = x + (size_t)node*128;
    #pragma unroll
    for (int pass = 0; pass < 2; ++pass) {
        int c = lane + pass*64;
        float accC, accS;
        if (c < 32) {
            float s1 = 0.f, s2 = 0.f;
            #pragma unroll
            for (int uu = 0; uu < 32; ++uu) {
                s1 += M[uu]      * WA0[uu*32 + c]
                   +  M[32 + uu] * WB0[uu*32 + c];
                s2 += xr[uu] * Wsc0[uu*32 + c];
            }
            accC = s1 * a8; accS = s2 * as32;
        } else {
            int cc = c - 32; int w = cc / 3, d = cc - 3*w;
            float s1 = 0.f, s2 = 0.f;
            #pragma unroll
            for (int uu = 0; uu < 32; ++uu) {
                s1 += M[64  + uu*3 + d] * WC1[uu*32 + w]
                   +  M[160 + uu*3 + d] * WD1[uu*32 + w];
                s2 += xr[32 + uu*3 + d] * Wsc1[uu*32 + w];
            }
            accC = s1 * a8; accS = s2 * as32;
        }
        out[(size_t)node*128 + c] = cs*accS + sn*accC;
    }
}

extern "C" void kernel_launch(void* const* d_in, const int* in_sizes, int n_in,
                              void* d_out, int out_size, void* d_ws, size_t ws_size,
                              hipStream_t stream) {
    const float* node_input = (const float*)d_in[0];
    const float* node_attr  = (const float*)d_in[1];
    const int*   edge_src   = (const int*)  d_in[2];
    const int*   edge_dst   = (const int*)  d_in[3];
    const float* edge_attr  = (const float*)d_in[4];
    const float* edge_scal  = (const float*)d_in[5];
    const float* W_sc0 = (const float*)d_in[6];
    const float* W_sc1 = (const float*)d_in[7];
    const float* W_l10 = (const float*)d_in[8];
    const float* W_l11 = (const float*)d_in[9];
    const float* W_fc1 = (const float*)d_in[10];
    const float* W_fc2 = (const float*)d_in[11];
    const float* W_A0  = (const float*)d_in[12];
    const float* W_B0  = (const float*)d_in[13];
    const float* W_C1  = (const float*)d_in[14];
    const float* W_D1  = (const float*)d_in[15];
    const float* W_3A  = (const float*)d_in[16];
    const float* W_3B  = (const float*)d_in[17];
    float* out = (float*)d_out;

    // ws layout: f 25.6MB | cnt 0.2MB | idx 19.2MB | weight 204.8MB (f16)
    const size_t f_b   = (size_t)N_NODES*128*4;          // 25,600,000
    const size_t cnt_b = (size_t)N_NODES*4;              //    200,000
    const size_t idx_b = (size_t)N_NODES*CAP*4;          // 19,200,000
    float* f   = (float*)d_ws;
    int*   cnt = (int*)((char*)d_ws + f_b);
    int*   idx = (int*)((char*)d_ws + f_b + cnt_b);
    _Float16* weight = (_Float16*)((char*)d_ws + f_b + cnt_b + idx_b);
    const size_t need = f_b + cnt_b + idx_b + (size_t)N_EDGES*128*2;

    k_node_f<<<N_NODES, 128, 0, stream>>>(node_input, node_attr, W_l10, W_l11, f);
    k_zero  <<<(N_NODES + 255)/256, 256, 0, stream>>>(cnt);
    k_ticket<<<(N_EDGES + 255)/256, 256, 0, stream>>>(edge_dst, cnt, idx);

    if (ws_size >= need) {
        k_edge_w<<<2048, 256, 0, stream>>>(edge_scal, edge_attr, W_fc1, W_fc2, weight);
        k_main  <<<(N_NODES + 3)/4, 256, 0, stream>>>(node_input, node_attr, edge_src,
                  edge_attr, weight, W_sc0, W_sc1, W_A0, W_B0, W_C1, W_D1,
                  W_3A, W_3B, f, cnt, idx, out);
    } else {
        k_main_fused<<<(N_NODES + 3)/4, 256, 0, stream>>>(node_input, node_attr, edge_src,
                  edge_attr, edge_scal, W_sc0, W_sc1, W_fc1, W_fc2,
                  W_A0, W_B0, W_C1, W_D1, W_3A, W_3B, f, cnt, idx, out);
    }
}

// Round 6
// 474.899 us; speedup vs baseline: 1.2627x; 1.2627x over previous
//
#include <hip/hip_runtime.h>
#include <stdint.h>

#define N_NODES 50000
#define N_EDGES 800000
#define CAP 96            // max tracked in-degree; Poisson(16) tops out ~45
#define NTILES (N_EDGES/16)

typedef _Float16 f16x8 __attribute__((ext_vector_type(8)));
typedef _Float16 f16x2 __attribute__((ext_vector_type(2)));
typedef float    f32x4 __attribute__((ext_vector_type(4)));

// ---------------- K1: f = fctp_scalar(x, attr, W_l1_0, W_l1_1) ----------------
// PLANE layout: f[n][0..32) = f0[u];  f[n][32 + d*32 + w] = f1[w][d]  (d=0,1,2)
__global__ __launch_bounds__(128) void k_node_f(
        const float* __restrict__ x, const float* __restrict__ attr,
        const float* __restrict__ W0, const float* __restrict__ W1,
        float* __restrict__ f)
{
    int n = blockIdx.x;
    int t = threadIdx.x;
    __shared__ float xs[128];
    xs[t] = x[(size_t)n*128 + t];
    __syncthreads();
    float a = attr[n] * 0.17677669529663689f;   // attr / sqrt(32)
    float acc = 0.f;
    if (t < 32) {
        #pragma unroll
        for (int u = 0; u < 32; ++u) acc += xs[u] * W0[u*32 + t];
    } else {
        int c = t - 32; int d = c >> 5, w = c & 31;
        #pragma unroll
        for (int u = 0; u < 32; ++u) acc += xs[32 + u*3 + d] * W1[u*32 + w];
    }
    f[(size_t)n*128 + t] = acc * a;
}

// ---------------- K2: per-dst edge lists (atomic ticket) ----------------
__global__ void k_zero(int* __restrict__ cnt) {
    int i = blockIdx.x*256 + threadIdx.x;
    if (i < N_NODES) cnt[i] = 0;
}

__global__ void k_ticket(const int* __restrict__ dst, int* __restrict__ cnt,
                         int* __restrict__ idx) {
    int e = blockIdx.x*256 + threadIdx.x;
    if (e >= N_EDGES) return;
    int d = dst[e];
    int slot = atomicAdd(&cnt[d], 1);
    if (slot < CAP) idx[d*CAP + slot] = e;
}

// ---------------- K3: edge-parallel MLP -> weight[e][128] f16 ----------------
// Output layout per edge row (dword pairs): dwords [0,32) = (wA[u]*e0*0.25, wC[u]*0.25),
// dwords [32,64) = (wD[u]*e0*0.25, wB[u]*0.25/sqrt3).  One dword per (half,u).
__global__ __launch_bounds__(256) void k_edge_w(
    const float* __restrict__ escal, const float* __restrict__ eattr,
    const float* __restrict__ Wfc1, const float* __restrict__ Wfc2,
    _Float16* __restrict__ weight)
{
    __shared__ __align__(16) _Float16 lds_h[4][16][72];
    __shared__ __align__(16) uint32_t lds_o[4][16][64];

    const int wv   = threadIdx.x >> 6;
    const int lane = threadIdx.x & 63;
    const int rl   = lane & 15;
    const int g4   = lane >> 4;

    // MFMA B-fragments of W_fc1/W_fc2 (f16, 1/8 folded)
    f16x8 w1f[2][4];
    #pragma unroll
    for (int ks = 0; ks < 2; ++ks)
      #pragma unroll
      for (int jt = 0; jt < 4; ++jt)
        #pragma unroll
        for (int i = 0; i < 8; ++i)
          w1f[ks][jt][i] = (_Float16)(Wfc1[(ks*32 + g4*8 + i)*64 + jt*16 + rl] * 0.125f);
    f16x8 w2f[2][8];
    #pragma unroll
    for (int ks = 0; ks < 2; ++ks)
      #pragma unroll
      for (int jt = 0; jt < 8; ++jt)
        #pragma unroll
        for (int i = 0; i < 8; ++i)
          w2f[ks][jt][i] = (_Float16)(Wfc2[(ks*32 + g4*8 + i)*128 + jt*16 + rl] * 0.125f);

    const int w  = blockIdx.x*4 + wv;
    const int t0 = w*7;
    const int t1 = (t0 + 7 < NTILES) ? t0 + 7 : NTILES;

    for (int tt = t0; tt < t1; ++tt) {
        const int eb = tt*16;
        // A-frags: 16 edge rows of escal
        f16x8 af[2];
        #pragma unroll
        for (int ks = 0; ks < 2; ++ks) {
            const float* p = escal + (size_t)(eb + rl)*64 + ks*32 + g4*8;
            float4 lo = *(const float4*)(p);
            float4 hi = *(const float4*)(p + 4);
            af[ks][0]=(_Float16)lo.x; af[ks][1]=(_Float16)lo.y;
            af[ks][2]=(_Float16)lo.z; af[ks][3]=(_Float16)lo.w;
            af[ks][4]=(_Float16)hi.x; af[ks][5]=(_Float16)hi.y;
            af[ks][6]=(_Float16)hi.z; af[ks][7]=(_Float16)hi.w;
        }
        float e0L = eattr[(size_t)(eb + rl)*4];

        // h = es @ (W1/8)
        f32x4 hacc[4];
        #pragma unroll
        for (int jt = 0; jt < 4; ++jt) {
            f32x4 z = {0.f,0.f,0.f,0.f};
            z = __builtin_amdgcn_mfma_f32_16x16x32_f16(af[0], w1f[0][jt], z, 0,0,0);
            z = __builtin_amdgcn_mfma_f32_16x16x32_f16(af[1], w1f[1][jt], z, 0,0,0);
            hacc[jt] = z;
        }
        // silu*1.679, transpose via LDS
        #pragma unroll
        for (int jt = 0; jt < 4; ++jt)
          #pragma unroll
          for (int r = 0; r < 4; ++r) {
            float v = hacc[jt][r];
            float s = 1.679f * v / (1.f + __expf(-v));
            lds_h[wv][g4*4 + r][jt*16 + rl] = (_Float16)s;
          }
        f16x8 a2[2];
        #pragma unroll
        for (int ks = 0; ks < 2; ++ks)
            a2[ks] = *reinterpret_cast<const f16x8*>(&lds_h[wv][rl][ks*32 + g4*8]);

        // wfull = h @ (W2/8)
        f32x4 z[8];
        #pragma unroll
        for (int jt = 0; jt < 8; ++jt) {
            f32x4 zz = {0.f,0.f,0.f,0.f};
            zz = __builtin_amdgcn_mfma_f32_16x16x32_f16(a2[0], w2f[0][jt], zz, 0,0,0);
            zz = __builtin_amdgcn_mfma_f32_16x16x32_f16(a2[1], w2f[1][jt], zz, 0,0,0);
            z[jt] = zz;
        }

        // scale + permute into dword pairs, f16 pack
        #pragma unroll
        for (int pg = 0; pg < 2; ++pg)
          #pragma unroll
          for (int r = 0; r < 4; ++r) {
            float e0r = __shfl(e0L, g4*4 + r);
            float loA = z[pg][r]     * (0.25f * e0r);
            float hiC = z[2 + pg][r] * 0.25f;
            float loD = z[4 + pg][r] * (0.25f * e0r);
            float hiB = z[6 + pg][r] * 0.14433756729740643f;   // 0.25/sqrt(3)
            uint32_t pAC = __builtin_bit_cast(uint32_t, __builtin_amdgcn_cvt_pkrtz(loA, hiC));
            uint32_t pDB = __builtin_bit_cast(uint32_t, __builtin_amdgcn_cvt_pkrtz(loD, hiB));
            lds_o[wv][g4*4 + r][pg*16 + rl]      = pAC;
            lds_o[wv][g4*4 + r][32 + pg*16 + rl] = pDB;
          }

        // coalesced copy-out: 16 rows x 256B
        uint32_t* wg = (uint32_t*)weight + (size_t)tt*1024;
        const uint32_t* lo32 = &lds_o[wv][0][0];
        #pragma unroll
        for (int p = 0; p < 4; ++p) {
            uint4 v = *(const uint4*)(lo32 + p*256 + lane*4);
            *(uint4*)(wg + p*256 + lane*4) = v;
        }
    }
}

// ---------------- K4: gather + reduce + node transform (no MFMA) ----------------
__global__ __launch_bounds__(256, 6) void k_main(
    const float* __restrict__ x, const float* __restrict__ attr,
    const int*   __restrict__ esrc, const float* __restrict__ eattr,
    const _Float16* __restrict__ weight,
    const float* __restrict__ Wsc0, const float* __restrict__ Wsc1,
    const float* __restrict__ WA0,  const float* __restrict__ WB0,
    const float* __restrict__ WC1,  const float* __restrict__ WD1,
    const float* __restrict__ W3A,  const float* __restrict__ W3B,
    const float* __restrict__ f,    const int* __restrict__ cnt,
    const int*   __restrict__ idx,  float* __restrict__ out)
{
    __shared__ float lds_m[4][256];   // mA[0,32) mB[32,64) mC[64,160) mD[160,256)

    const int wv   = threadIdx.x >> 6;
    const int lane = threadIdx.x & 63;
    const int u    = lane & 31;
    const int half = lane >> 5;
    const int node = blockIdx.x*4 + wv;
    if (node >= N_NODES) return;

    const uint32_t* wq = (const uint32_t*)weight;
    int deg = min(cnt[node], CAP);

    float mAB = 0.f, mCD0 = 0.f, mCD1 = 0.f, mCD2 = 0.f;

    for (int tb = 0; tb < deg; tb += 64) {
        int myi  = tb + lane;
        int eidL = (myi < deg) ? idx[node*CAP + myi] : 0;
        int srcL = (myi < deg) ? esrc[eidL] : 0;
        float4 eaT = make_float4(0.f,0.f,0.f,0.f);
        if (myi < deg) eaT = *(const float4*)(eattr + (size_t)eidL*4);
        int rows = min(64, deg - tb);

        for (int b = 0; b < rows; b += 8) {
            int nb = min(8, rows - b);
            uint32_t wp[8]; float gA[8], gB[8], gC[8];
            #pragma unroll
            for (int j = 0; j < 8; ++j) if (j < nb) {
                int mm = b + j;
                int e  = __shfl(eidL, mm);
                int sm = __shfl(srcL, mm);
                wp[j] = wq[(size_t)e*64 + half*32 + u];
                const float* gb = f + (size_t)sm*128;
                if (half == 0) { gA[j] = gb[u]; }
                else { gA[j] = gb[32 + u]; gB[j] = gb[64 + u]; gC[j] = gb[96 + u]; }
            }
            #pragma unroll
            for (int j = 0; j < 8; ++j) if (j < nb) {
                int mm = b + j;
                float e1x = __shfl(eaT.y, mm);
                float e1y = __shfl(eaT.z, mm);
                float e1z = __shfl(eaT.w, mm);
                f16x2 wh = __builtin_bit_cast(f16x2, wp[j]);
                float lo = (float)wh[0], hi = (float)wh[1];
                if (half == 0) {
                    mAB += lo * gA[j];                       // mA (e0,0.25 folded)
                    float tc = hi * gA[j];                   // wC*g0*0.25
                    mCD0 += tc*e1x; mCD1 += tc*e1y; mCD2 += tc*e1z;
                } else {
                    mAB += hi * (gA[j]*e1x + gB[j]*e1y + gC[j]*e1z);  // mB
                    mCD0 += lo*gA[j]; mCD1 += lo*gB[j]; mCD2 += lo*gC[j];  // mD
                }
            }
        }
    }

    float* M = lds_m[wv];
    if (half == 0) {
        M[u] = mAB;
        M[64  + u*3 + 0] = mCD0; M[64  + u*3 + 1] = mCD1; M[64  + u*3 + 2] = mCD2;
    } else {
        M[32 + u] = mAB;
        M[160 + u*3 + 0] = mCD0; M[160 + u*3 + 1] = mCD1; M[160 + u*3 + 2] = mCD2;
    }

    float a    = attr[node];
    float a8   = a * 0.125f;
    float as32 = a * 0.17677669529663689f;

    const float w3 = (half == 0) ? W3A[u] : W3B[u];
    float tpart = (half == 0) ? M[u] * w3 : M[32 + u] * w3;
    #pragma unroll
    for (int off = 32; off > 0; off >>= 1) tpart += __shfl_xor(tpart, off);
    float angle = 0.1f * tpart * a8;
    float sn, cs; __sincosf(angle, &sn, &cs);

    const float* xr = x + (size_t)node*128;
    #pragma unroll
    for (int pass = 0; pass < 2; ++pass) {
        int c = lane + pass*64;
        float accC, accS;
        if (c < 32) {
            float s1 = 0.f, s2 = 0.f;
            #pragma unroll
            for (int uu = 0; uu < 32; ++uu) {
                s1 += M[uu]      * WA0[uu*32 + c]
                   +  M[32 + uu] * WB0[uu*32 + c];
                s2 += xr[uu] * Wsc0[uu*32 + c];
            }
            accC = s1 * a8; accS = s2 * as32;
        } else {
            int cc = c - 32; int w = cc / 3, d = cc - 3*w;
            float s1 = 0.f, s2 = 0.f;
            #pragma unroll
            for (int uu = 0; uu < 32; ++uu) {
                s1 += M[64  + uu*3 + d] * WC1[uu*32 + w]
                   +  M[160 + uu*3 + d] * WD1[uu*32 + w];
                s2 += xr[32 + uu*3 + d] * Wsc1[uu*32 + w];
            }
            accC = s1 * a8; accS = s2 * as32;
        }
        out[(size_t)node*128 + c] = cs*accS + sn*accC;
    }
}

// ---------------- Fallback: fused kernel (used when ws too small) ----------------
__global__ __launch_bounds__(256) void k_main_fused(
    const float* __restrict__ x, const float* __restrict__ attr,
    const int*   __restrict__ esrc, const float* __restrict__ eattr,
    const float* __restrict__ escal,
    const float* __restrict__ Wsc0, const float* __restrict__ Wsc1,
    const float* __restrict__ Wfc1, const float* __restrict__ Wfc2,
    const float* __restrict__ WA0,  const float* __restrict__ WB0,
    const float* __restrict__ WC1,  const float* __restrict__ WD1,
    const float* __restrict__ W3A,  const float* __restrict__ W3B,
    const float* __restrict__ f,    const int* __restrict__ cnt,
    const int*   __restrict__ idx,  float* __restrict__ out)
{
    __shared__ __align__(16) _Float16 lds_h[4][16][72];
    __shared__ float lds_w[4][16][132];
    __shared__ float lds_m[4][256];

    const int wv   = threadIdx.x >> 6;
    const int lane = threadIdx.x & 63;
    const int node = blockIdx.x*4 + wv;
    if (node >= N_NODES) return;
    const int rl   = lane & 15;
    const int g4   = lane >> 4;
    const int u    = lane & 31;
    const int half = lane >> 5;

    f16x8 w1f[2][4];
    #pragma unroll
    for (int ks = 0; ks < 2; ++ks)
      #pragma unroll
      for (int jt = 0; jt < 4; ++jt)
        #pragma unroll
        for (int i = 0; i < 8; ++i)
          w1f[ks][jt][i] = (_Float16)(Wfc1[(ks*32 + g4*8 + i)*64 + jt*16 + rl] * 0.125f);
    f16x8 w2f[2][8];
    #pragma unroll
    for (int ks = 0; ks < 2; ++ks)
      #pragma unroll
      for (int jt = 0; jt < 8; ++jt)
        #pragma unroll
        for (int i = 0; i < 8; ++i)
          w2f[ks][jt][i] = (_Float16)(Wfc2[(ks*32 + g4*8 + i)*128 + jt*16 + rl] * 0.125f);

    int deg  = min(cnt[node], CAP);
    int eid0 = (lane      < deg) ? idx[node*CAP + lane]      : 0;
    int eid1 = (lane + 64 < deg) ? idx[node*CAP + 64 + lane] : 0;

    float mAB = 0.f, mCD0 = 0.f, mCD1 = 0.f, mCD2 = 0.f;

    int ntile = (deg + 15) >> 4;
    for (int t = 0; t < ntile; ++t) {
        int sl = t*16 + rl; sl = min(sl, deg - 1);
        int eA = __shfl(eid0, sl & 63);
        int eB = __shfl(eid1, (sl - 64) & 63);
        int er = (sl < 64) ? eA : eB;
        f16x8 af[2];
        #pragma unroll
        for (int ks = 0; ks < 2; ++ks) {
            const float* p = escal + (size_t)er*64 + ks*32 + g4*8;
            float4 lo = *(const float4*)(p);
            float4 hi = *(const float4*)(p + 4);
            af[ks][0]=(_Float16)lo.x; af[ks][1]=(_Float16)lo.y;
            af[ks][2]=(_Float16)lo.z; af[ks][3]=(_Float16)lo.w;
            af[ks][4]=(_Float16)hi.x; af[ks][5]=(_Float16)hi.y;
            af[ks][6]=(_Float16)hi.z; af[ks][7]=(_Float16)hi.w;
        }

        f32x4 hacc[4];
        #pragma unroll
        for (int jt = 0; jt < 4; ++jt) {
            f32x4 z = {0.f,0.f,0.f,0.f};
            z = __builtin_amdgcn_mfma_f32_16x16x32_f16(af[0], w1f[0][jt], z, 0,0,0);
            z = __builtin_amdgcn_mfma_f32_16x16x32_f16(af[1], w1f[1][jt], z, 0,0,0);
            hacc[jt] = z;
        }
        #pragma unroll
        for (int jt = 0; jt < 4; ++jt)
          #pragma unroll
          for (int r = 0; r < 4; ++r) {
            float v = hacc[jt][r];
            float s = 1.679f * v / (1.f + __expf(-v));
            lds_h[wv][g4*4 + r][jt*16 + rl] = (_Float16)s;
          }
        f16x8 a2[2];
        #pragma unroll
        for (int ks = 0; ks < 2; ++ks)
            a2[ks] = *reinterpret_cast<const f16x8*>(&lds_h[wv][rl][ks*32 + g4*8]);

        #pragma unroll
        for (int jt = 0; jt < 8; ++jt) {
            f32x4 z = {0.f,0.f,0.f,0.f};
            z = __builtin_amdgcn_mfma_f32_16x16x32_f16(a2[0], w2f[0][jt], z, 0,0,0);
            z = __builtin_amdgcn_mfma_f32_16x16x32_f16(a2[1], w2f[1][jt], z, 0,0,0);
            #pragma unroll
            for (int r = 0; r < 4; ++r)
                lds_w[wv][g4*4 + r][jt*16 + rl] = z[r];
        }

        int rows = min(16, deg - t*16);
        for (int mm = 0; mm < rows; ++mm) {
            int s2 = t*16 + mm;
            int e = (s2 < 64) ? __shfl(eid0, s2) : __shfl(eid1, (s2 - 64) & 63);
            e = __builtin_amdgcn_readfirstlane(e);
            int   src  = esrc[e];
            float ea0  = eattr[(size_t)e*4 + 0];
            float ea1x = eattr[(size_t)e*4 + 1];
            float ea1y = eattr[(size_t)e*4 + 2];
            float ea1z = eattr[(size_t)e*4 + 3];
            float wPr = lds_w[wv][mm][half*64 + u];
            float wSe = lds_w[wv][mm][32 + half*64 + u];
            const float* gb = f + (size_t)src*128;
            if (half == 0) {
                float g0 = gb[u];
                mAB += wPr * g0 * ea0;
                float tc = wSe * g0;
                mCD0 += tc * ea1x; mCD1 += tc * ea1y; mCD2 += tc * ea1z;
            } else {
                float g1x = gb[32 + u];
                float g1y = gb[64 + u];
                float g1z = gb[96 + u];
                float dotB = g1x*ea1x + g1y*ea1y + g1z*ea1z;
                mAB += wSe * dotB * 0.57735026918962576f;
                float td = wPr * ea0;
                mCD0 += td*g1x; mCD1 += td*g1y; mCD2 += td*g1z;
            }
        }
    }

    mAB *= 0.25f; mCD0 *= 0.25f; mCD1 *= 0.25f; mCD2 *= 0.25f;

    float* M = lds_m[wv];
    if (half == 0) {
        M[u] = mAB;
        M[64  + u*3 + 0] = mCD0; M[64  + u*3 + 1] = mCD1; M[64  + u*3 + 2] = mCD2;
    } else {
        M[32 + u] = mAB;
        M[160 + u*3 + 0] = mCD0; M[160 + u*3 + 1] = mCD1; M[160 + u*3 + 2] = mCD2;
    }

    float a    = attr[node];
    float a8   = a * 0.125f;
    float as32 = a * 0.17677669529663689f;

    const float w3 = (half == 0) ? W3A[u] : W3B[u];
    float tpart = (half == 0) ? M[u] * w3 : M[32 + u] * w3;
    #pragma unroll
    for (int off = 32; off > 0; off >>= 1) tpart += __shfl_xor(tpart, off);
    float angle = 0.1f * tpart * a8;
    float sn, cs; __sincosf(angle, &sn, &cs);

    const float* xr = x + (size_t)node*128;
    #pragma unroll
    for (int pass = 0; pass < 2; ++pass) {
        int c = lane + pass*64;
        float accC, accS;
        if (c < 32) {
            float s1 = 0.f, s2 = 0.f;
            #pragma unroll
            for (int uu = 0; uu < 32; ++uu) {
                s1 += M[uu]      * WA0[uu*32 + c]
                   +  M[32 + uu] * WB0[uu*32 + c];
                s2 += xr[uu] * Wsc0[uu*32 + c];
            }
            accC = s1 * a8; accS = s2 * as32;
        } else {
            int cc = c - 32; int w = cc / 3, d = cc - 3*w;
            float s1 = 0.f, s2 = 0.f;
            #pragma unroll
            for (int uu = 0; uu < 32; ++uu) {
                s1 += M[64  + uu*3 + d] * WC1[uu*32 + w]
                   +  M[160 + uu*3 + d] * WD1[uu*32 + w];
                s2 += xr[32 + uu*3 + d] * Wsc1[uu*32 + w];
            }
            accC = s1 * a8; accS = s2 * as32;
        }
        out[(size_t)node*128 + c] = cs*accS + sn*accC;
    }
}

extern "C" void kernel_launch(void* const* d_in, const int* in_sizes, int n_in,
                              void* d_out, int out_size, void* d_ws, size_t ws_size,
                              hipStream_t stream) {
    const float* node_input = (const float*)d_in[0];
    const float* node_attr  = (const float*)d_in[1];
    const int*   edge_src   = (const int*)  d_in[2];
    const int*   edge_dst   = (const int*)  d_in[3];
    const float* edge_attr  = (const float*)d_in[4];
    const float* edge_scal  = (const float*)d_in[5];
    const float* W_sc0 = (const float*)d_in[6];
    const float* W_sc1 = (const float*)d_in[7];
    const float* W_l10 = (const float*)d_in[8];
    const float* W_l11 = (const float*)d_in[9];
    const float* W_fc1 = (const float*)d_in[10];
    const float* W_fc2 = (const float*)d_in[11];
    const float* W_A0  = (const float*)d_in[12];
    const float* W_B0  = (const float*)d_in[13];
    const float* W_C1  = (const float*)d_in[14];
    const float* W_D1  = (const float*)d_in[15];
    const float* W_3A  = (const float*)d_in[16];
    const float* W_3B  = (const float*)d_in[17];
    float* out = (float*)d_out;

    // ws layout: f 25.6MB | cnt 0.2MB | idx 19.2MB | weight 204.8MB (f16)
    const size_t f_b   = (size_t)N_NODES*128*4;          // 25,600,000
    const size_t cnt_b = (size_t)N_NODES*4;              //    200,000
    const size_t idx_b = (size_t)N_NODES*CAP*4;          // 19,200,000
    float* f   = (float*)d_ws;
    int*   cnt = (int*)((char*)d_ws + f_b);
    int*   idx = (int*)((char*)d_ws + f_b + cnt_b);
    _Float16* weight = (_Float16*)((char*)d_ws + f_b + cnt_b + idx_b);
    const size_t need = f_b + cnt_b + idx_b + (size_t)N_EDGES*128*2;

    k_node_f<<<N_NODES, 128, 0, stream>>>(node_input, node_attr, W_l10, W_l11, f);
    k_zero  <<<(N_NODES + 255)/256, 256, 0, stream>>>(cnt);
    k_ticket<<<(N_EDGES + 255)/256, 256, 0, stream>>>(edge_dst, cnt, idx);

    if (ws_size >= need) {
        k_edge_w<<<2048, 256, 0, stream>>>(edge_scal, edge_attr, W_fc1, W_fc2, weight);
        k_main  <<<(N_NODES + 3)/4, 256, 0, stream>>>(node_input, node_attr, edge_src,
                  edge_attr, weight, W_sc0, W_sc1, W_A0, W_B0, W_C1, W_D1,
                  W_3A, W_3B, f, cnt, idx, out);
    } else {
        k_main_fused<<<(N_NODES + 3)/4, 256, 0, stream>>>(node_input, node_attr, edge_src,
                  edge_attr, edge_scal, W_sc0, W_sc1, W_fc1, W_fc2,
                  W_A0, W_B0, W_C1, W_D1, W_3A, W_3B, f, cnt, idx, out);
    }
}